// Round 7
// baseline (119.775 us; speedup 1.0000x reference)
//
#include <hip/hip_runtime.h>
#include <math.h>

#define Bc 8
#define Hc 128
#define Wc 128
#define Cc 20
#define Gc 64
#define HWc (Hc*Wc)          // 16384
#define NBLK2 (Bc*HWc/128)   // 1024 main blocks, 128 pixels each (2 thr/pixel)

// per-image workspace layout (floats), stride WS_STRIDE
//  box4[64] (by1,bx1,by2,bx2) AoS at 0..255
//  red4[64] (fgy,fgx,0.5/sy,0.5/sx) class-sorted AoS at 256..511
//  kpix int[64] class-sorted at 512; seg int[64] orig order at 576
//  starts int[22] at 640; nv f at 704; acc f[6] at 705; slice int at 712
#define WS_STRIDE 768
#define OFF_BOX   0
#define OFF_RED   256
#define OFF_KPIX  512
#define OFF_SEG   576
#define OFF_START 640
#define WS_NV     704
#define WS_ACC    705
#define WS_SLICE  712

__global__ __launch_bounds__(64) void prep_kernel(
    const float* __restrict__ gt, const float* __restrict__ sy,
    const float* __restrict__ sx, float* __restrict__ ws)
{
  const int b = blockIdx.x;
  const int g = threadIdx.x;
  const float* row = gt + (size_t)(b*Gc + g)*7;
  const float cy = row[0];
  const float cx = row[1];

  // wave argmin over cy with first-index tie-break (== jnp.argmin)
  float v = cy; int idx = g;
  #pragma unroll
  for (int o = 32; o > 0; o >>= 1) {
    const float ov = __shfl_down(v, o, 64);
    const int   oi = __shfl_down(idx, o, 64);
    if (ov < v || (ov == v && oi < idx)) { v = ov; idx = oi; }
  }
  const int slice = __shfl(idx, 0, 64);
  const bool valid = g < slice;
  const int cid = (int)row[6] - 1;
  const int cls = (cid >= 0 && cid < Cc) ? cid : Cc;   // bucket 20 = bad class

  __shared__ int counts[Cc+1], offs[Cc+1], starts[Cc+2];
  if (g < Cc+1) { counts[g] = 0; offs[g] = 0; }
  __syncthreads();
  if (valid) atomicAdd(&counts[cls], 1);
  __syncthreads();
  if (g == 0) {
    int acc = 0;
    for (int c = 0; c < Cc+1; ++c) { starts[c] = acc; acc += counts[c]; }
    starts[Cc+1] = acc;
  }
  __syncthreads();

  float* wb = ws + (size_t)b*WS_STRIDE;
  int*  wbi = (int*)wb;
  float4 bx;
  bx.x = (row[2]+0.5f)*0.25f;  // by1
  bx.y = (row[3]+0.5f)*0.25f;  // bx1
  bx.z = (row[4]+0.5f)*0.25f;  // by2
  bx.w = (row[5]+0.5f)*0.25f;  // bx2
  ((float4*)(wb + OFF_BOX))[g] = bx;
  wbi[OFF_SEG+g] = (valid && cls < Cc) ? cls : Cc;
  if (valid) {
    const int pos = starts[cls] + atomicAdd(&offs[cls], 1);  // bucket order irrelevant (max/or)
    float4 rp;
    rp.x = floorf((cy+0.5f)*0.25f);
    rp.y = floorf((cx+0.5f)*0.25f);
    rp.z = 0.5f / sy[b*Gc+g];   // 0.5 factor folded in (red arg = -(dy^2*z + dx^2*w))
    rp.w = 0.5f / sx[b*Gc+g];
    ((float4*)(wb + OFF_RED))[pos] = rp;
    int kpy = (int)floorf(cy*0.25f); kpy = kpy < 0 ? 0 : (kpy > Hc-1 ? Hc-1 : kpy);
    int kpx = (int)floorf(cx*0.25f); kpx = kpx < 0 ? 0 : (kpx > Wc-1 ? Wc-1 : kpx);
    wbi[OFF_KPIX+pos] = kpy*Wc + kpx;
  }
  if (g < Cc+2) wbi[OFF_START+g] = starts[g];
  if (g == 0) { wb[WS_NV] = fmaxf((float)slice, 1.0f); wbi[WS_SLICE] = slice; }
  if (g < 6) wb[WS_ACC+g] = 0.0f;
}

__device__ __forceinline__ float wave_sum(float v) {
  #pragma unroll
  for (int o = 32; o > 0; o >>= 1) v += __shfl_down(v, o, 64);
  return v;
}

// 2 threads per pixel: lanes ln and ln^32 of a wave co-process one pixel.
// Pass 1 splits gts by interleaved 4-gt chunks (ci = 2*c2 + half); pass 2
// splits the 20 classes 10/10 by float4 group. Combines via __shfl_xor(32):
// no LDS, no barriers, no fences. Identical control flow per half (data-
// divergent only) so the wave runs half the per-pixel instructions.
__global__ __launch_bounds__(256, 4) void main_kernel(
  const float* __restrict__ kpt, const float* __restrict__ preg,
  const float* __restrict__ fpn, const float* __restrict__ masks,
  const float* __restrict__ wsc, float* __restrict__ wsa)
{
  __shared__ float s_part[4][6];

  const int tid = threadIdx.x;
  const int wv = tid >> 6, ln = tid & 63;
  const int half = ln >> 5, sub = ln & 31;
  const int pi  = wv*32 + sub;                 // 0..127 pixel-in-block
  const int pix = blockIdx.x*128 + pi;
  const int b   = blockIdx.x >> 7;             // 128 blocks per image
  const int hw  = pix & (HWc-1);
  const int h = hw >> 7, w = hw & (Wc-1);

  const float* wb  = wsc + (size_t)b*WS_STRIDE;     // read-only view
  const int*   wbi = (const int*)wb;
  const float4* __restrict__ box4 = (const float4*)(wb + OFF_BOX);
  const float4* __restrict__ red4 = (const float4*)(wb + OFF_RED);
  const int nslice = wbi[WS_SLICE];                 // wave-uniform -> s_load

  const float wx = w + 0.5f, hy = h + 0.5f;
  const float px_ = (float)w, py_ = (float)h;
  const float4* mrow4 = (const float4*)(masks + (size_t)pix*Gc);

  // hoisted independent loads: latency hides under pass 1
  const float4 p4 = *(const float4*)(preg + (size_t)pix*4);
  const float4* kq4 = (const float4*)(kpt + (size_t)pix*Cc);
  const float4* fq4 = (const float4*)(fpn + (size_t)pix*Cc);
  const float4 kg0 = kq4[half], kg1 = kq4[2+half], kg2 = kq4[4];
  const float4 fg0 = fq4[half], fg1 = fq4[2+half], fg2 = fq4[4];

  // ---- pass 1: this half processes chunks ci = 2*c2 + half (4 gts each),
  //      2-chunk-ahead rolling prefetch, per-g validity predication ----
  float amin = 3.0e38f, loc = 0.f, mmin = 0.f; int gmin = 0;
  const int nC2 = (nslice + 7) >> 3;           // wave-uniform trip count
  float4 mc0 = mrow4[half];                    // always in-bounds (16 float4s/row)
  float4 mc1 = mrow4[2 + half];
  for (int c2 = 0; c2 < nC2; ++c2) {
    const int pfci = 2*(c2+2) + half;
    const float4 mn = mrow4[pfci < 16 ? pfci : (14+half)];  // clamped prefetch
    const int ci = 2*c2 + half;
    #pragma unroll
    for (int j = 0; j < 4; ++j) {
      const int g = ci*4 + j;
      const float m = (j==0)?mc0.x:(j==1)?mc0.y:(j==2)?mc0.z:mc0.w;
      const float4 bx = box4[g];               // 2 addrs/wave, L1-hot
      const float dl = wx - bx.y, dr = bx.w - wx;
      const float dt = hy - bx.x, db = bx.z - hy;
      const bool inb = (dl > 0.f) & (dr > 0.f) & (dt > 0.f) & (db > 0.f)
                       & (g < nslice);
      const float hm = inb ? m : 0.f;
      const float area = (dl*hm + dr*hm) * (dt*hm + db*hm);
      const float ap = area + (1.f - hm)*1e8f; // invalid g -> exactly 1e8 (ref pad)
      if (ap < amin) { amin = ap; gmin = g; mmin = m; }
      loc = fmaxf(loc, hm);
    }
    mc0 = mc1; mc1 = mn;
  }
  // combine halves: lexmin over (ap, g) == sequential first-min semantics
  {
    const float o_amin = __shfl_xor(amin, 32, 64);
    const int   o_gmin = __shfl_xor(gmin, 32, 64);
    const float o_mmin = __shfl_xor(mmin, 32, 64);
    const float o_loc  = __shfl_xor(loc , 32, 64);
    if (o_amin < amin || (o_amin == amin && o_gmin < gmin)) {
      amin = o_amin; gmin = o_gmin; mmin = o_mmin;
    }
    loc = fmaxf(loc, o_loc);
  }

  // ---- dist_mask nonzero only at gmin (both halves compute; only half 0
  //      contributes the per-pixel terms) ----
  float dlm=0.f, drm=0.f, dtm=0.f, dbm=0.f, hmval=0.f; int cmin = Cc;
  if (loc > 0.f) {
    const float4 bx = box4[gmin];
    const float dl = wx - bx.y, dr = bx.w - wx;
    const float dt = hy - bx.x, db = bx.z - hy;
    const float area = (dl*mmin + dr*mmin) * (dt*mmin + db*mmin);
    if (area == amin) {                        // unpadded==padded-min semantics
      dlm = dl*mmin*loc; drm = dr*mmin*loc; dtm = dt*mmin*loc; dbm = db*mmin*loc;
      cmin = wbi[OFF_SEG + gmin];
      hmval = loc;
    }
  }

  // ---- pass 2: half 0 -> classes {0-3,8-11,16,17}; half 1 -> {4-7,12-15,18,19}
  //      exp-of-max: ONE exp per class (max(exp)==exp(max); empty: exp(-1e30)=+0) ----
  float gargmax = -1e30f, grav = 0.f, hneg = 0.f;
  #pragma unroll
  for (int grp = 0; grp < 2; ++grp) {
    const int idx = 2*grp + half;
    const float4 kq = grp ? kg1 : kg0;
    const float4 fq = grp ? fg1 : fg0;
    #pragma unroll
    for (int j = 0; j < 4; ++j) {
      const int c = idx*4 + j;
      const int s0 = wbi[OFF_START + c];
      const int s1 = wbi[OFF_START + c + 1];
      float ramax = -1e30f; bool kpv = false;
      for (int i = s0; i < s1; ++i) {          // short data-divergent scan
        const float4 rp = red4[i];
        const int kpix = wbi[OFF_KPIX + i];
        const float dy = py_ - rp.x, dx = px_ - rp.y;
        const float arg = -(dy*dy*rp.z + dx*dx*rp.w);
        ramax = fmaxf(ramax, arg);
        kpv = kpv | (kpix == hw);
      }
      const float rmax = __expf(ramax);        // 0 exactly for empty bucket
      gargmax = fmaxf(gargmax, ramax);
      // shared-exp sigmoid + log-sigmoid
      const float x  = (j==0)?kq.x:(j==1)?kq.y:(j==2)?kq.z:kq.w;
      const float e  = __expf(-fabsf(x));
      const float t  = 1.f + e;
      const float r  = 1.f / t;
      const float L  = __logf(t);
      const float s  = (x >= 0.f) ? r : e*r;
      const float lsx = fminf(x, 0.f) - L;
      const float kv = kpv ? 1.f : 0.f;
      const float om = 1.f - rmax;
      const float om4 = (om*om)*(om*om);
      const float oms = 1.f - s;
      grav += (-(oms*oms)*lsx)*kv + (-om4*(s*s)*(lsx - x))*(1.f - kv);

      const float fx  = (j==0)?fq.x:(j==1)?fq.y:(j==2)?fq.z:fq.w;
      const float ef  = __expf(-fabsf(fx));
      const float tf  = 1.f + ef;
      const float rf  = 1.f / tf;
      const float Lf  = __logf(tf);
      const float sf  = (fx >= 0.f) ? rf : ef*rf;
      const float lsf = fminf(fx, 0.f) - Lf;
      hneg += -10.f*(sf*sf)*(lsf - fx);        // hg=0 baseline; fixed up below
    }
  }
  // tail classes 16+2*half+j (j=0,1), components 2*half+j of kg2/fg2
  #pragma unroll
  for (int j = 0; j < 2; ++j) {
    const int c = 16 + 2*half + j;
    const int cp = 2*half + j;
    const int s0 = wbi[OFF_START + c];
    const int s1 = wbi[OFF_START + c + 1];
    float ramax = -1e30f; bool kpv = false;
    for (int i = s0; i < s1; ++i) {
      const float4 rp = red4[i];
      const int kpix = wbi[OFF_KPIX + i];
      const float dy = py_ - rp.x, dx = px_ - rp.y;
      const float arg = -(dy*dy*rp.z + dx*dx*rp.w);
      ramax = fmaxf(ramax, arg);
      kpv = kpv | (kpix == hw);
    }
    const float rmax = __expf(ramax);
    gargmax = fmaxf(gargmax, ramax);
    const float x  = (cp==0)?kg2.x:(cp==1)?kg2.y:(cp==2)?kg2.z:kg2.w;
    const float e  = __expf(-fabsf(x));
    const float t  = 1.f + e;
    const float r  = 1.f / t;
    const float L  = __logf(t);
    const float s  = (x >= 0.f) ? r : e*r;
    const float lsx = fminf(x, 0.f) - L;
    const float kv = kpv ? 1.f : 0.f;
    const float om = 1.f - rmax;
    const float om4 = (om*om)*(om*om);
    const float oms = 1.f - s;
    grav += (-(oms*oms)*lsx)*kv + (-om4*(s*s)*(lsx - x))*(1.f - kv);

    const float fx  = (cp==0)?fg2.x:(cp==1)?fg2.y:(cp==2)?fg2.z:fg2.w;
    const float ef  = __expf(-fabsf(fx));
    const float tf  = 1.f + ef;
    const float rf  = 1.f / tf;
    const float Lf  = __logf(tf);
    const float sf  = (fx >= 0.f) ? rf : ef*rf;
    const float lsf = fminf(fx, 0.f) - Lf;
    hneg += -10.f*(sf*sf)*(lsf - fx);
  }
  // bucket 20 (invalid-class gts): iou_red arg only; half 1 scans it
  if (half) {
    const int s0  = wbi[OFF_START + Cc];
    const int e20 = wbi[OFF_START + Cc + 1];
    for (int i = s0; i < e20; ++i) {
      const float4 rp = red4[i];
      const float dy = py_ - rp.x, dx = px_ - rp.y;
      gargmax = fmaxf(gargmax, -(dy*dy*rp.z + dx*dx*rp.w));
    }
  }
  gargmax = fmaxf(gargmax, __shfl_xor(gargmax, 32, 64));
  const float iou_red = __expf(gargmax);       // 0 exactly if no valid gts

  // ---- iou term (half 0 contributes) ----
  const float inter = (fminf(dlm,p4.x)+fminf(drm,p4.y)) * (fminf(dtm,p4.z)+fminf(dbm,p4.w));
  const float uni = (dlm+drm)*(dtm+dbm) + (p4.x+p4.y)*(p4.z+p4.w) - inter;
  const float iou = inter / (uni + 1e-12f);
  const float t_iou = -__logf(iou + 1e-12f) * loc * (iou_red*4.f + 1.f);

  // ---- hm fixup at cmin: exactly once per pixel (half 0) ----
  float hpos = 0.f, shg = 0.f;
  if (half == 0 && hmval > 0.f && cmin < Cc) {
    const float fx  = fpn[(size_t)pix*Cc + cmin];  // L1-hot reload
    const float ef  = __expf(-fabsf(fx));
    const float tf  = 1.f + ef;
    const float rf  = 1.f / tf;
    const float Lf  = __logf(tf);
    const float sf  = (fx >= 0.f) ? rf : ef*rf;
    const float lsf = fminf(fx, 0.f) - Lf;
    const float osf = 1.f - sf;
    hpos = -10.f*(osf*osf)*lsf*hmval;
    hneg -= (-10.f*(sf*sf)*(lsf - fx))*hmval;   // corrects whichever half added it
    shg = hmval;
  }

  // ---- block reduction (per-pixel terms contributed by half 0 only) ----
  const float zi = half ? 0.f : 1.f;
  float v0 = wave_sum(t_iou * zi);
  float v1 = wave_sum(loc * zi);
  float v2 = wave_sum(grav);
  float v3 = wave_sum(hpos);
  float v4 = wave_sum(hneg);
  float v5 = wave_sum(shg);
  if (ln == 0) {
    s_part[wv][0]=v0; s_part[wv][1]=v1; s_part[wv][2]=v2;
    s_part[wv][3]=v3; s_part[wv][4]=v4; s_part[wv][5]=v5;
  }
  __syncthreads();
  if (tid < 6) {
    const float a = s_part[0][tid] + s_part[1][tid] + s_part[2][tid] + s_part[3][tid];
    atomicAdd(wsa + (size_t)b*WS_STRIDE + WS_ACC + tid, a);
  }
}

__global__ __launch_bounds__(64) void fin_kernel(const float* __restrict__ ws,
                                                 float* __restrict__ out)
{
  const int b = threadIdx.x;
  float total = 0.0f;
  if (b < Bc) {
    const float* wb = ws + (size_t)b*WS_STRIDE;
    const float iou_loss = wb[WS_ACC+0];
    const float s_loc    = wb[WS_ACC+1];
    const float grav     = wb[WS_ACC+2];
    const float hposs    = wb[WS_ACC+3];
    const float hnegs    = wb[WS_ACC+4];
    const float shg      = wb[WS_ACC+5];
    const float nv       = wb[WS_NV];
    const float hm_loss  = hnegs / ((float)(HWc*Cc) - shg);
    const bool  cond     = (shg != 0.0f);
    const float safe_hg  = cond ? shg : 1.0f;
    const float safe_loc = (s_loc > 0.0f) ? s_loc : 1.0f;
    const float hm2      = hm_loss + hposs/safe_hg;
    total = cond ? (iou_loss/safe_loc + grav/nv + hm2) : hm_loss;
  }
  #pragma unroll
  for (int o = 4; o > 0; o >>= 1) total += __shfl_down(total, o, 64);
  if (b == 0) out[0] = total * (1.0f/(float)Bc);
}

extern "C" void kernel_launch(void* const* d_in, const int* in_sizes, int n_in,
                              void* d_out, int out_size, void* d_ws, size_t ws_size,
                              hipStream_t stream) {
  const float* kpt  = (const float*)d_in[0];  // keypoints  [B,H,W,C]
  const float* preg = (const float*)d_in[1];  // preg       [B,H,W,4]
  const float* fpn  = (const float*)d_in[2];  // fpn        [B,H,W,C]
  const float* gt   = (const float*)d_in[3];  // gt         [B,G,7]
  const float* mk   = (const float*)d_in[4];  // masks      [B,H,W,G]
  const float* sy   = (const float*)d_in[5];  // scalar_y   [B,G]
  const float* sx   = (const float*)d_in[6];  // scalar_x   [B,G]
  float* ws  = (float*)d_ws;
  float* out = (float*)d_out;

  prep_kernel<<<Bc, 64, 0, stream>>>(gt, sy, sx, ws);
  main_kernel<<<NBLK2, 256, 0, stream>>>(kpt, preg, fpn, mk, ws, ws);
  fin_kernel<<<1, 64, 0, stream>>>(ws, out);
}